// Round 13
// baseline (154.317 us; speedup 1.0000x reference)
//
#include <hip/hip_runtime.h>
#include <hip/hip_bf16.h>
#include <math.h>

typedef __attribute__((ext_vector_type(8))) short bf16x8;
typedef __attribute__((ext_vector_type(4))) float f32x4;
typedef __attribute__((ext_vector_type(16))) float f32x16;

__device__ __forceinline__ short f2bs(float f) {   // fp32 -> bf16 RNE via hw cvt
    union { __hip_bfloat16 b; short s; } u;
    u.b = __float2bfloat16(f);
    return u.s;
}

__device__ __forceinline__ unsigned short f2b_int(float f) {  // prep path (cold)
    union { float f; unsigned int u; } x; x.f = f;
    unsigned int r = x.u + 0x7FFFu + ((x.u >> 16) & 1u);
    return (unsigned short)(r >> 16);
}

// gelu(x) = x*sigmoid(2y), y = 0.7978845608*x*(1+0.044715*x^2)   (tanh-form, hw exp2)
__device__ __forceinline__ float gelu_t(float x) {
    float x2 = x * x;
    float z  = x * fmaf(0.10294324f, x2, 2.3022082f);
    float e  = __builtin_amdgcn_exp2f(z);
    float r  = __builtin_amdgcn_rcpf(1.0f + e);
    return fmaf(x, -r, x);          // x*(1-r)
}

// prep: w1t[n*64+k] = W1cat[k][n]  (n<64: W1top col n, n>=64: W1bot col n-64)
//       w2t[n*64+k] = W2[k][n];  attn = softmax(edge_attn) rows
__global__ void prep_k(const float* __restrict__ W1, const float* __restrict__ W2,
                       const float* __restrict__ ea, unsigned short* __restrict__ w1t,
                       unsigned short* __restrict__ w2t, float* __restrict__ attn)
{
    int gid = blockIdx.x * 256 + threadIdx.x;
    if (gid < 128 * 64) {
        int n = gid >> 6, k = gid & 63;
        float v = (n < 64) ? W1[k * 64 + n] : W1[(64 + k) * 64 + (n - 64)];
        w1t[gid] = f2b_int(v);
    } else if (gid < 12288) {
        int idx = gid - 8192;
        int n = idx >> 6, k = idx & 63;
        w2t[idx] = f2b_int(W2[k * 64 + n]);
    }
    if (gid < 9) {
        int i = gid / 3, j = gid % 3;
        float e0 = ea[i*3+0], e1 = ea[i*3+1], e2 = ea[i*3+2];
        float mx = fmaxf(e0, fmaxf(e1, e2));
        float d = expf(e0-mx) + expf(e1-mx) + expf(e2-mx);
        attn[gid] = expf(ea[i*3+j] - mx) / d;
    }
}

// 32x32x16 MFMA version: one M-tile = 32 padded rows = 8 batches per wave-iter.
// A/B frag: lane holds row/col (lane&31), k = (lane>>5)*8 + e.
// C frag:   col = lane&31, row = (reg&3) + 8*(reg>>2) + 4*(lane>>5)  [m74/m101]
__global__ __launch_bounds__(256, 3)
void edge_mfma10(const float* __restrict__ nodes,
                 const unsigned short* __restrict__ w1t,
                 const unsigned short* __restrict__ w2t,
                 const float* __restrict__ attn9,
                 const float* __restrict__ b1,
                 const float* __restrict__ b2,
                 float* __restrict__ out)
{
    // per-wave G tile [32 rows][64 cols] bf16, XOR-swizzled: 4 waves * 4KB = 16KB
    __shared__ __align__(16) unsigned short Gs[4 * 32 * 64];

    const int t = threadIdx.x;
    const int lane = t & 63, wave = t >> 6;
    const int m = lane & 31, hi = lane >> 5;
    unsigned short* Gw = Gs + wave * (32 * 64);

    const int bL  = m >> 2;                  // batch-in-8 for A rows
    const int iA  = m & 3;
    const int iAr = (iA == 3) ? 0 : iA;      // dummy row -> re-read row 0

    // attn weights pinned to SGPRs (wave-uniform, indexed by compile-time i,j)
    float aw[9];
    #pragma unroll
    for (int i = 0; i < 9; ++i) {
        union { float f; int u; } c; c.f = attn9[i];
        c.u = __builtin_amdgcn_readfirstlane(c.u);
        aw[i] = c.f;
    }
    // per-lane bias slices: feature col c = un*32 + m ; out col d = dt*32 + m
    float b1c[2] = { b1[m], b1[32 + m] };
    float b2c[2] = { b2[m], b2[32 + m] };

    // ---- weight B-frags: lane = col (m), k = t4*16 + hi*8 + e ----
    bf16x8 w1u[2][4], w1v[2][4], w2f[2][4];
    #pragma unroll
    for (int un = 0; un < 2; ++un)
        #pragma unroll
        for (int t4 = 0; t4 < 4; ++t4) {
            w1u[un][t4] = *(const bf16x8*)&w1t[(un*32 + m) * 64 + t4*16 + hi*8];
            w1v[un][t4] = *(const bf16x8*)&w1t[(64 + un*32 + m) * 64 + t4*16 + hi*8];
        }
    #pragma unroll
    for (int dt = 0; dt < 2; ++dt)
        #pragma unroll
        for (int t4 = 0; t4 < 4; ++t4)
            w2f[dt][t4] = *(const bf16x8*)&w2t[(dt*32 + m) * 64 + t4*16 + hi*8];

    #pragma unroll
    for (int it = 0; it < 2; ++it) {
        const int gb8 = blockIdx.x * 64 + it * 32 + wave * 8;   // 8 batches this wave-iter

        // ---- A-frags: lane = padded row m, k = t4*16 + hi*8 + e ----
        bf16x8 af[4];
        const float* xb = nodes + ((long)(gb8 + bL) * 3 + iAr) * 64 + hi * 8;
        #pragma unroll
        for (int t4 = 0; t4 < 4; ++t4) {
            f32x4 p0 = *(const f32x4*)(xb + t4 * 16);
            f32x4 p1 = *(const f32x4*)(xb + t4 * 16 + 4);
            #pragma unroll
            for (int e = 0; e < 4; ++e) { af[t4][e] = f2bs(p0[e]); af[t4][4+e] = f2bs(p1[e]); }
        }

        // ---- GEMM1 (U,V) + lane-local gelu mix, per 32-feature tile un ----
        #pragma unroll
        for (int un = 0; un < 2; ++un) {
            f32x16 aU, aV;
            #pragma unroll
            for (int e = 0; e < 16; ++e) { aU[e] = 0.f; aV[e] = 0.f; }
            #pragma unroll
            for (int t4 = 0; t4 < 4; ++t4)
                aU = __builtin_amdgcn_mfma_f32_32x32x16_bf16(af[t4], w1u[un][t4], aU, 0, 0, 0);
            #pragma unroll
            for (int t4 = 0; t4 < 4; ++t4)
                aV = __builtin_amdgcn_mfma_f32_32x32x16_bf16(af[t4], w1v[un][t4], aV, 0, 0, 0);

            const float b1v = b1c[un];
            #pragma unroll
            for (int kq = 0; kq < 4; ++kq) {
                // regs 4kq+r -> padded row r + 8kq + 4hi ; quad = one batch, reg-local
                float u0 = aU[4*kq+0] + b1v;
                float u1 = aU[4*kq+1] + b1v;
                float u2 = aU[4*kq+2] + b1v;
                float gg0 = 0.f, gg1 = 0.f, gg2 = 0.f;
                #pragma unroll
                for (int j = 0; j < 3; ++j) {
                    float vj = aV[4*kq+j];
                    float gl0 = gelu_t(u0 + vj);
                    float gl1 = gelu_t(u1 + vj);
                    float gl2 = gelu_t(u2 + vj);
                    gg0 = fmaf(aw[0*3+j], gl0, gg0);
                    gg1 = fmaf(aw[1*3+j], gl1, gg1);
                    gg2 = fmaf(aw[2*3+j], gl2, gg2);
                }
                const int r0 = 8*kq + 4*hi;
                const int c  = un*32 + m;
                // XOR-swizzle (short units): idx = row*64 + (col ^ ((row&7)<<3))
                Gw[(r0+0)*64 + (c ^ (((r0+0)&7) << 3))] = (unsigned short)f2bs(gg0);
                Gw[(r0+1)*64 + (c ^ (((r0+1)&7) << 3))] = (unsigned short)f2bs(gg1);
                Gw[(r0+2)*64 + (c ^ (((r0+2)&7) << 3))] = (unsigned short)f2bs(gg2);
            }
        }
        // same-wave DS ordering: lgkmcnt inserted by compiler before dependent reads

        // ---- GEMM2: A = G via swizzled b128 reads (lane = row m), B = W2 ----
        bf16x8 ga[4];
        #pragma unroll
        for (int t4 = 0; t4 < 4; ++t4)
            ga[t4] = *(const bf16x8*)&Gw[m*64 + ((t4*16 + hi*8) ^ ((m & 7) << 3))];

        #pragma unroll
        for (int dt = 0; dt < 2; ++dt) {
            f32x16 acc;
            #pragma unroll
            for (int e = 0; e < 16; ++e) acc[e] = 0.f;
            #pragma unroll
            for (int t4 = 0; t4 < 4; ++t4)
                acc = __builtin_amdgcn_mfma_f32_32x32x16_bf16(ga[t4], w2f[dt][t4], acc, 0, 0, 0);

            const float b2v = b2c[dt];
            #pragma unroll
            for (int kq = 0; kq < 4; ++kq) {
                #pragma unroll
                for (int i = 0; i < 3; ++i) {            // skip dummy row i==3
                    const int bat = gb8 + 2*kq + hi;     // row = i + 8kq + 4hi -> batch 2kq+hi
                    __builtin_nontemporal_store(acc[4*kq + i] + b2v,
                        out + ((long)bat * 3 + i) * 64 + dt*32 + m);
                }
            }
        }
    }
}

extern "C" void kernel_launch(void* const* d_in, const int* in_sizes, int n_in,
                              void* d_out, int out_size, void* d_ws, size_t ws_size,
                              hipStream_t stream)
{
    const float* nodes = (const float*)d_in[0];
    const float* W1    = (const float*)d_in[1];
    const float* b1    = (const float*)d_in[2];
    const float* W2    = (const float*)d_in[3];
    const float* b2    = (const float*)d_in[4];
    const float* ea    = (const float*)d_in[5];
    float* out = (float*)d_out;

    unsigned short* w1t = (unsigned short*)d_ws;          // 8192 shorts
    unsigned short* w2t = w1t + 8192;                     // 4096 shorts
    float* attn = (float*)(w2t + 4096);                   // 9 floats

    prep_k<<<48, 256, 0, stream>>>(W1, W2, ea, w1t, w2t, attn);

    const int groups = (out_size / 64) / 3 / 64;          // 4096 blocks of 64 batches
    edge_mfma10<<<groups, 256, 0, stream>>>(nodes, w1t, w2t, attn, b1, b2, out);
}

// Round 15
// 81.538 us; speedup vs baseline: 1.8926x; 1.8926x over previous
//
#include <hip/hip_runtime.h>
#include <hip/hip_bf16.h>
#include <math.h>

typedef __attribute__((ext_vector_type(8))) short bf16x8;
typedef __attribute__((ext_vector_type(4))) float f32x4;

#define WSTR 68     // G-buffer row stride in shorts (136B): conflict-free frag reads

__device__ __forceinline__ short f2bs(float f) {   // fp32 -> bf16 RNE via hw cvt
    union { __hip_bfloat16 b; short s; } u;
    u.b = __float2bfloat16(f);
    return u.s;
}

__device__ __forceinline__ unsigned short f2b_int(float f) {  // prep path (cold)
    union { float f; unsigned int u; } x; x.f = f;
    unsigned int r = x.u + 0x7FFFu + ((x.u >> 16) & 1u);
    return (unsigned short)(r >> 16);
}

// gelu(x) = x*sigmoid(2y), y = 0.7978845608*x*(1+0.044715*x^2)   (tanh-form, hw exp2)
__device__ __forceinline__ float gelu_t(float x) {
    float x2 = x * x;
    float z  = x * fmaf(0.10294324f, x2, 2.3022082f);
    float e  = __builtin_amdgcn_exp2f(z);
    float r  = __builtin_amdgcn_rcpf(1.0f + e);
    return fmaf(x, -r, x);          // x*(1-r)
}

// prep: w1t[n*64+k] = W1cat[k][n]  (n<64: W1top col n, n>=64: W1bot col n-64)
//       w2t[n*64+k] = W2[k][n]  (appended at n=128..191);  attn = softmax rows
__global__ void prep_k(const float* __restrict__ W1, const float* __restrict__ W2,
                       const float* __restrict__ ea, unsigned short* __restrict__ w1t,
                       unsigned short* __restrict__ w2t, float* __restrict__ attn)
{
    int gid = blockIdx.x * 256 + threadIdx.x;
    if (gid < 128 * 64) {
        int n = gid >> 6, k = gid & 63;
        float v = (n < 64) ? W1[k * 64 + n] : W1[(64 + k) * 64 + (n - 64)];
        w1t[gid] = f2b_int(v);
    } else if (gid < 12288) {
        int idx = gid - 8192;
        int n = idx >> 6, k = idx & 63;
        w2t[idx] = f2b_int(W2[k * 64 + n]);
    }
    if (gid < 9) {
        int i = gid / 3, j = gid % 3;
        float e0 = ea[i*3+0], e1 = ea[i*3+1], e2 = ea[i*3+2];
        float mx = fmaxf(e0, fmaxf(e1, e2));
        float d = expf(e0-mx) + expf(e1-mx) + expf(e2-mx);
        attn[gid] = expf(ea[i*3+j] - mx) / d;
    }
}

// weight fragment from swizzled LDS tile: row in [0,192), 16B-granular XOR swizzle
#define WFRAG(Ws, row, ks) \
    (*(const bf16x8*)&(Ws)[(row) * 64 + ((((ks)*32) + q*8) ^ (((row) & 7) << 3))])

__global__ __launch_bounds__(256, 3)
void edge_mfma11(const float* __restrict__ nodes,
                 const unsigned short* __restrict__ wsrc,   // w1cat+w2, 12288 shorts
                 const float* __restrict__ attn9,
                 const float* __restrict__ b1,
                 const float* __restrict__ b2,
                 float* __restrict__ out)
{
    __shared__ __align__(16) unsigned short Ws[12288];        // 24 KB swizzled weights
    __shared__ __align__(16) unsigned short Gs[4 * 16 * WSTR]; // 8.7 KB G transpose

    const int t = threadIdx.x;
    const int lane = t & 63, wave = t >> 6;
    const int q = lane >> 4, r16 = lane & 15;
    unsigned short* Gw = Gs + wave * 16 * WSTR;               // wave-private

    // ---- stage weights global -> LDS with 16B-granular XOR swizzle ----
    // global chunk c (16B = 8 shorts): row n = c>>3, k8 = c&7 ; dst k8' = k8 ^ (n&7)
    {
        const ulonglong2* src = (const ulonglong2*)wsrc;
        ulonglong2* dst = (ulonglong2*)Ws;
        #pragma unroll
        for (int i = 0; i < 6; ++i) {
            int c = t + i * 256;                              // 1536 chunks
            int n = c >> 3, k8 = c & 7;
            dst[(c & ~7) | (k8 ^ (n & 7))] = src[c];
        }
    }

    // padded tile row r16 -> batch-in-group bA, node-row iA (iA==3 is the dummy row)
    const int bA = r16 >> 2;
    const int iA = r16 & 3;
    const int iAr = (iA == 3) ? 0 : iA;

    // uniform attn weights (SGPR-pinned), per-lane bias slices
    float aw[9];
    #pragma unroll
    for (int i = 0; i < 9; ++i) {
        union { float f; int u; } c; c.f = attn9[i];
        c.u = __builtin_amdgcn_readfirstlane(c.u);
        aw[i] = c.f;
    }
    float b1c[4], b2c[4];
    #pragma unroll
    for (int nt = 0; nt < 4; ++nt) { b1c[nt] = b1[nt*16 + r16]; b2c[nt] = b2[nt*16 + r16]; }

    const int batch0 = blockIdx.x * 64 + wave * 16;

    __syncthreads();   // weights staged

    #pragma unroll
    for (int mt = 0; mt < 4; ++mt) {
        // ---- X -> A-frags straight from global (k = ks*32 + q*8 + e) ----
        const long rowA = ((long)(batch0 + mt*4 + bA)) * 3 + iAr;
        const f32x4* xp = (const f32x4*)(nodes + rowA * 64 + q * 8);
        f32x4 x0 = xp[0], x1 = xp[1], x2v = xp[8], x3 = xp[9];
        bf16x8 afr0, afr1;
        #pragma unroll
        for (int e = 0; e < 4; ++e) {
            afr0[e]   = f2bs(x0[e]);  afr0[4+e] = f2bs(x1[e]);
            afr1[e]   = f2bs(x2v[e]); afr1[4+e] = f2bs(x3[e]);
        }

        // ---- GEMM1 + lane-local gelu mix, per 16-col tile; weights from LDS ----
        #pragma unroll
        for (int nt = 0; nt < 4; ++nt) {
            f32x4 z = {0.f, 0.f, 0.f, 0.f};
            z = __builtin_amdgcn_mfma_f32_16x16x32_bf16(afr0, WFRAG(Ws, nt*16 + r16, 0), z, 0, 0, 0);
            z = __builtin_amdgcn_mfma_f32_16x16x32_bf16(afr1, WFRAG(Ws, nt*16 + r16, 1), z, 0, 0, 0);
            f32x4 y = {0.f, 0.f, 0.f, 0.f};
            y = __builtin_amdgcn_mfma_f32_16x16x32_bf16(afr0, WFRAG(Ws, 64 + nt*16 + r16, 0), y, 0, 0, 0);
            y = __builtin_amdgcn_mfma_f32_16x16x32_bf16(afr1, WFRAG(Ws, 64 + nt*16 + r16, 1), y, 0, 0, 0);

            // lane holds batch q: u rows z[0..2], v rows y[0..2], col nt*16+r16
            float u0 = z[0] + b1c[nt], u1 = z[1] + b1c[nt], u2 = z[2] + b1c[nt];
            float gg0 = 0.f, gg1 = 0.f, gg2 = 0.f;
            #pragma unroll
            for (int j = 0; j < 3; ++j) {
                float vj = y[j];
                float gl0 = gelu_t(u0 + vj);
                float gl1 = gelu_t(u1 + vj);
                float gl2 = gelu_t(u2 + vj);
                gg0 = fmaf(aw[0*3+j], gl0, gg0);
                gg1 = fmaf(aw[1*3+j], gl1, gg1);
                gg2 = fmaf(aw[2*3+j], gl2, gg2);
            }
            Gw[(q*4 + 0) * WSTR + nt*16 + r16] = (unsigned short)f2bs(gg0);
            Gw[(q*4 + 1) * WSTR + nt*16 + r16] = (unsigned short)f2bs(gg1);
            Gw[(q*4 + 2) * WSTR + nt*16 + r16] = (unsigned short)f2bs(gg2);
        }
        // same-wave DS ordering: compiler emits lgkmcnt before dependent reads

        // ---- GEMM2: A = G via wave-private LDS transpose, B = W2 from LDS ----
        bf16x8 gfr0 = *(const bf16x8*)&Gw[r16 * WSTR + q*8];
        bf16x8 gfr1 = *(const bf16x8*)&Gw[r16 * WSTR + 32 + q*8];
        #pragma unroll
        for (int nt = 0; nt < 4; ++nt) {
            f32x4 acc = {0.f, 0.f, 0.f, 0.f};
            acc = __builtin_amdgcn_mfma_f32_16x16x32_bf16(gfr0, WFRAG(Ws, 128 + nt*16 + r16, 0), acc, 0, 0, 0);
            acc = __builtin_amdgcn_mfma_f32_16x16x32_bf16(gfr1, WFRAG(Ws, 128 + nt*16 + r16, 1), acc, 0, 0, 0);
            // C: row = q*4 + r (r<3 real rows of batch q), col = nt*16 + r16
            float* op = out + ((long)(batch0 + mt*4 + q) * 3) * 64 + nt*16 + r16;
            #pragma unroll
            for (int r = 0; r < 3; ++r)
                __builtin_nontemporal_store(acc[r] + b2c[nt], op + r * 64);
        }
    }
}

extern "C" void kernel_launch(void* const* d_in, const int* in_sizes, int n_in,
                              void* d_out, int out_size, void* d_ws, size_t ws_size,
                              hipStream_t stream)
{
    const float* nodes = (const float*)d_in[0];
    const float* W1    = (const float*)d_in[1];
    const float* b1    = (const float*)d_in[2];
    const float* W2    = (const float*)d_in[3];
    const float* b2    = (const float*)d_in[4];
    const float* ea    = (const float*)d_in[5];
    float* out = (float*)d_out;

    unsigned short* w1t = (unsigned short*)d_ws;          // 8192 shorts (w1cat)
    unsigned short* w2t = w1t + 8192;                     // 4096 shorts (w2), contiguous
    float* attn = (float*)(w2t + 4096);                   // 9 floats

    prep_k<<<48, 256, 0, stream>>>(W1, W2, ea, w1t, w2t, attn);

    const int groups = (out_size / 64) / 3 / 64;          // 4096 blocks of 64 batches
    edge_mfma11<<<groups, 256, 0, stream>>>(nodes, w1t, attn, b1, b2, out);
}